// Round 15
// baseline (149.290 us; speedup 1.0000x reference)
//
#include <hip/hip_runtime.h>
#include <hip/hip_fp16.h>

static constexpr int HH = 2048;
static constexpr int WW = 2048;
static constexpr int PADT = 24;   // top/bottom pad rows
static constexpr int PADL = 8;    // left/right pad cols
static constexpr int SW   = WW + 2 * PADL;          // 2064
static constexpr int PROWS = HH + 2 * PADT;         // 2096
static constexpr size_t PadElems = (size_t)PROWS * SW;
static constexpr int RSP = 8;     // rows/thread, slant passes (packed, 2 cols/thread)
static constexpr int RV = 16;     // rows/thread, vertical passes

// segment tables for +10 deg: lval(d)=round(d*tan(10deg))
__device__ constexpr int CS[9] = {-24,-19,-14,-8,-2, 3, 9,15,20};
__device__ constexpr int CE[9] = {-20,-15, -9,-3, 2, 8,14,19,24};
__device__ constexpr int CO[9] = { -4, -3, -2,-1, 0, 1, 2, 3, 4};

union U32H2 { unsigned u; __half2 h; };
__device__ __forceinline__ __half2 u2h(unsigned u) { U32H2 x; x.u = u; return x.h; }
__device__ __forceinline__ unsigned h2u(__half2 h) { U32H2 x; x.h = h; return x.u; }

// XCD band swizzles (bijective; bid%8 = XCD round-robin assumption, perf-only).
__device__ __forceinline__ void swz_s2(int& bx, int& by) {
  const int bid = blockIdx.x;             // 0..1023
  const int xcd = bid & 7, i = bid >> 3;  // i: 0..127
  by = xcd * 32 + (i & 31);
  bx = i >> 5;                            // 0..3
}
__device__ __forceinline__ void swz_v(int& bx, int& by) {
  const int bid = blockIdx.x;             // 0..511
  const int xcd = bid & 7, i = bid >> 3;  // i: 0..63
  by = xcd * 16 + (i & 15);
  bx = i >> 4;                            // 0..3
}

// ---- one slanted segment, packed half2, 2 cols (w2, w2+1), run [SS,EE] at offset OO ----
template<int SS, int EE, int OO, int NROWS>
__device__ __forceinline__ void seg2p(const __half* __restrict__ tp, int h0, int w2,
                                      __half2* __restrict__ acc) {
  constexpr int NR = EE - SS;             // L-1: 4 or 5
  constexpr bool EVEN = ((OO & 1) == 0);
  const size_t st = SW / 2;
  const unsigned* p = (const unsigned*)(tp + (size_t)(h0 + SS + PADT) * SW +
                                        (w2 + PADL + (EVEN ? OO : OO - 1)));
  unsigned ring[NR];
  __half2 s = u2h(0u);
#pragma unroll
  for (int k = 0; k < NR; ++k) {
    unsigned u;
    if constexpr (EVEN) { u = p[k * st]; }
    else { const unsigned ul = p[k * st], ur = p[k * st + 1]; u = (ul >> 16) | (ur << 16); }
    ring[k] = u;
    s = __hadd2(s, u2h(u));
  }
#pragma unroll
  for (int r = 0; r < NROWS; ++r) {
    unsigned u;
    if constexpr (EVEN) { u = p[(NR + r) * st]; }
    else { const unsigned ul = p[(NR + r) * st], ur = p[(NR + r) * st + 1]; u = (ul >> 16) | (ur << 16); }
    const __half2 v = u2h(u);
    acc[r] = __hadd2(acc[r], __hadd2(s, v));
    s = __hadd2(s, __hsub2(v, u2h(ring[r % NR])));
    ring[r % NR] = u;
  }
}

template<int SGN, int NROWS>   // +1 => +10deg, -1 => -10deg
__device__ __forceinline__ void filt_slant2p(const __half* __restrict__ tp, int h0, int w2,
                                             __half2* __restrict__ acc) {
#pragma unroll
  for (int r = 0; r < NROWS; ++r) acc[r] = u2h(0u);
  seg2p<-24, -20, -4 * SGN, NROWS>(tp, h0, w2, acc);
  seg2p<-19, -15, -3 * SGN, NROWS>(tp, h0, w2, acc);
  seg2p<-14,  -9, -2 * SGN, NROWS>(tp, h0, w2, acc);
  seg2p< -8,  -3, -1 * SGN, NROWS>(tp, h0, w2, acc);
  seg2p< -2,   2,  0      , NROWS>(tp, h0, w2, acc);
  seg2p<  3,   8,  1 * SGN, NROWS>(tp, h0, w2, acc);
  seg2p<  9,  14,  2 * SGN, NROWS>(tp, h0, w2, acc);
  seg2p< 15,  19,  3 * SGN, NROWS>(tp, h0, w2, acc);
  seg2p< 20,  24,  4 * SGN, NROWS>(tp, h0, w2, acc);
}

// analytic 1/N for the slant filters (A=0 => -10deg, A=2 => +10deg)
template<int A>
__device__ __forceinline__ float rcpcnt(int h, int w) {
  if (h >= 24 && h <= 2023 && w >= 4 && w <= 2043) return 1.0f / 49.0f;
  int cnt = 0;
  const int sgn = (A == 0) ? -1 : 1;
#pragma unroll
  for (int j = 0; j < 9; ++j) {
    const int ww = w + sgn * CO[j];
    const int ov = min(h + CE[j], HH - 1) - max(h + CS[j], 0) + 1;
    if (ww >= 0 && ww < WW && ov > 0) cnt += ov;
  }
  return 1.0f / (float)cnt;
}

// 1/N for the vertical filter
__device__ __forceinline__ float rcpcnt1(int h) {
  return 1.0f / (float)(min(h + 24, HH - 1) - max(h - 24, 0) + 1);
}

// ---- slant pass A: bp = filt(tcur)/N  (packed, 2 cols/thread) ----
template<int A>
__global__ __launch_bounds__(256) void passA(const __half* __restrict__ tcur,
                                             __half* __restrict__ bp) {
  int bx, by; swz_s2(bx, by);
  const int w2 = (bx * 256 + threadIdx.x) * 2;
  const int h0 = by * RSP;
  __half2 acc[RSP];
  filt_slant2p<(A == 0) ? -1 : 1, RSP>(tcur, h0, w2, acc);
#pragma unroll
  for (int r = 0; r < RSP; ++r) {
    const int h = h0 + r;
    const float2 f = __half22float2(acc[r]);
    *(unsigned*)(bp + (size_t)(h + PADT) * SW + (w2 + PADL)) =
        h2u(__floats2half2_rn(f.x * rcpcnt<A>(h, w2), f.y * rcpcnt<A>(h, w2 + 1)));
  }
}

// ---- slant pass B (mid): tcur -= filt(bp)/N (in place, packed) ----
template<int A>
__global__ __launch_bounds__(256) void passB(const __half* __restrict__ bp,
                                             __half* __restrict__ tcur) {
  int bx, by; swz_s2(bx, by);
  const int w2 = (bx * 256 + threadIdx.x) * 2;
  const int h0 = by * RSP;
  __half2 acc[RSP];
  filt_slant2p<(A == 0) ? -1 : 1, RSP>(bp, h0, w2, acc);
#pragma unroll
  for (int r = 0; r < RSP; ++r) {
    const int h = h0 + r;
    unsigned* o = (unsigned*)(tcur + (size_t)(h + PADT) * SW + (w2 + PADL));
    const float2 cur = __half22float2(u2h(*o));
    const float2 f = __half22float2(acc[r]);
    *o = h2u(__floats2half2_rn(cur.x - f.x * rcpcnt<A>(h, w2),
                               cur.y - f.y * rcpcnt<A>(h, w2 + 1)));
  }
}

// ---- final slant pass B: res = t0 - (tcur - filt(bp)/N); tcur <- res; global max ----
template<int A>
__global__ __launch_bounds__(256) void passBF(const __half* __restrict__ bp,
                                              __half* __restrict__ tcur,
                                              const __half* __restrict__ t0h,
                                              unsigned int* __restrict__ scaleU) {
  int bx, by; swz_s2(bx, by);
  const int w2 = (bx * 256 + threadIdx.x) * 2;
  const int h0 = by * RSP;
  __half2 acc[RSP];
  filt_slant2p<(A == 0) ? -1 : 1, RSP>(bp, h0, w2, acc);
  float m = 0.0f;
#pragma unroll
  for (int r = 0; r < RSP; ++r) {
    const int h = h0 + r;
    const float2 t0 = __half22float2(u2h(*(const unsigned*)(t0h + (size_t)h * WW + w2)));
    unsigned* o = (unsigned*)(tcur + (size_t)(h + PADT) * SW + (w2 + PADL));
    const float2 cur = __half22float2(u2h(*o));
    const float2 f = __half22float2(acc[r]);
    const float rx = t0.x - cur.x + f.x * rcpcnt<A>(h, w2);
    const float ry = t0.y - cur.y + f.y * rcpcnt<A>(h, w2 + 1);
    *o = h2u(__floats2half2_rn(rx, ry));
    m = fmaxf(m, fmaxf(fabsf(rx), fabsf(ry)));
  }
#pragma unroll
  for (int off = 32; off >= 1; off >>= 1) m = fmaxf(m, __shfl_xor(m, off));
  __shared__ float red[4];
  if ((threadIdx.x & 63) == 0) red[threadIdx.x >> 6] = m;
  __syncthreads();
  if (threadIdx.x == 0) {
    const float bm = fmaxf(fmaxf(red[0], red[1]), fmaxf(red[2], red[3]));
    atomicMax(scaleU, __float_as_uint(bm));
  }
}

// ---- vertical (0 deg) passes, packed half2, 2 cols/thread ----
__global__ __launch_bounds__(256) void passA1v(const __half* __restrict__ tcur,
                                               __half* __restrict__ bp) {
  int bx, by; swz_v(bx, by);
  const int w2 = (bx * 256 + threadIdx.x) * 2;
  const int h0 = by * RV;
  const size_t st = SW / 2;
  const unsigned* p = (const unsigned*)(tcur + (size_t)(h0 - 24 + PADT) * SW + (w2 + PADL));
  __half2 s = u2h(0u);
#pragma unroll
  for (int k = 0; k < 48; ++k) s = __hadd2(s, u2h(p[k * st]));
#pragma unroll
  for (int r = 0; r < RV; ++r) {
    const int h = h0 + r;
    const __half2 vin = u2h(p[(48 + r) * st]);
    const float2 f = __half22float2(__hadd2(s, vin));
    const float rc = rcpcnt1(h);
    *(unsigned*)(bp + (size_t)(h + PADT) * SW + (w2 + PADL)) =
        h2u(__floats2half2_rn(f.x * rc, f.y * rc));
    s = __hadd2(s, __hsub2(vin, u2h(p[r * st])));
  }
}

__global__ __launch_bounds__(256) void passB1v(const __half* __restrict__ bp,
                                               __half* __restrict__ tcur) {
  int bx, by; swz_v(bx, by);
  const int w2 = (bx * 256 + threadIdx.x) * 2;
  const int h0 = by * RV;
  const size_t st = SW / 2;
  const unsigned* p = (const unsigned*)(bp + (size_t)(h0 - 24 + PADT) * SW + (w2 + PADL));
  __half2 s = u2h(0u);
#pragma unroll
  for (int k = 0; k < 48; ++k) s = __hadd2(s, u2h(p[k * st]));
#pragma unroll
  for (int r = 0; r < RV; ++r) {
    const int h = h0 + r;
    const __half2 vin = u2h(p[(48 + r) * st]);
    const float2 f = __half22float2(__hadd2(s, vin));
    const float rc = rcpcnt1(h);
    unsigned* o = (unsigned*)(tcur + (size_t)(h + PADT) * SW + (w2 + PADL));
    const float2 cur = __half22float2(u2h(*o));
    *o = h2u(__floats2half2_rn(cur.x - f.x * rc, cur.y - f.y * rc));
    s = __hadd2(s, __hsub2(vin, u2h(p[r * st])));
  }
}

// ---- quantize D into 8-row-packed int8 cells, 2 cells/thread ----
__global__ __launch_bounds__(256) void quantV8(const __half* __restrict__ tcur,
                                               const unsigned int* __restrict__ scaleU,
                                               unsigned long long* __restrict__ V8) {
  const int i = blockIdx.x * 256 + threadIdx.x;   // over (HH/8) * (WW/2)
  const int s = i >> 10, x2 = (i & 1023) * 2;
  const float mg = __uint_as_float(*scaleU);
  const float inv = (mg > 0.0f) ? 127.0f / mg : 0.0f;
  const unsigned* base = (const unsigned*)(tcur + (size_t)(8 * s + PADT) * SW + (x2 + PADL));
  const size_t st = SW / 2;
  unsigned long long va = 0, vb = 0;
#pragma unroll
  for (int j = 0; j < 8; ++j) {
    const float2 f = __half22float2(u2h(base[(size_t)j * st]));
    const int qa = min(max((int)rintf(f.x * inv), -127), 127);
    const int qb = min(max((int)rintf(f.y * inv), -127), 127);
    va |= (unsigned long long)(unsigned char)(qa & 0xff) << (8 * j);
    vb |= (unsigned long long)(unsigned char)(qb & 0xff) << (8 * j);
  }
  unsigned long long* o = V8 + (size_t)s * WW + x2;
  o[0] = va; o[1] = vb;
}

// zero the pad frame of both fp16 staging buffers (+ init scaleU)
__global__ __launch_bounds__(64) void zeropad(__half* __restrict__ tp, __half* __restrict__ bp,
                                              unsigned int* __restrict__ scaleU) {
  if (blockIdx.x == 0 && blockIdx.y == 0 && threadIdx.x == 0) *scaleU = 0u;
  __half* buf = blockIdx.y ? bp : tp;
  const int row = blockIdx.x;
  __half* r = buf + (size_t)row * SW;
  const __half z = __float2half(0.0f);
  if (row < PADT || row >= PADT + HH) {
    for (int c = threadIdx.x; c < SW; c += 64) r[c] = z;
  } else if (threadIdx.x < PADL) {
    r[threadIdx.x] = z;
    r[PADL + WW + threadIdx.x] = z;
  }
}

// tcur interior = t0h = y - X, 4 px/thread via float4
__global__ __launch_bounds__(256) void sub2pad(const float* __restrict__ y,
                                               const float* __restrict__ X,
                                               __half* __restrict__ tcur,
                                               __half* __restrict__ t0h) {
  const int i = blockIdx.x * 256 + threadIdx.x;   // over n/4
  const int p = i * 4;
  const int h = p >> 11, w = p & (WW - 1);
  const float4 Y = ((const float4*)y)[i];
  const float4 Xv = ((const float4*)X)[i];
  union { __half2 h2; unsigned u; } a, b;
  a.h2 = __floats2half2_rn(Y.x - Xv.x, Y.y - Xv.y);
  b.h2 = __floats2half2_rn(Y.z - Xv.z, Y.w - Xv.w);
  uint2 o; o.x = a.u; o.y = b.u;
  *(uint2*)(tcur + (size_t)(h + PADT) * SW + (w + PADL)) = o;
  *(uint2*)(t0h + (size_t)p) = o;
}

// ---- gather, 2 px/thread: two independent bilinear chains per thread ----
__device__ __forceinline__ float gather_one(const unsigned long long* __restrict__ V8,
                                            float cx, float cy) {
  const float gx = fminf(fmaxf((cx + 1.0f) * 0.5f * (float)(WW - 1), 0.0f), (float)(WW - 1));
  const float gy = fminf(fmaxf((cy + 1.0f) * 0.5f * (float)(HH - 1), 0.0f), (float)(HH - 1));
  const float x0 = floorf(gx), y0 = floorf(gy);
  const float wx = gx - x0, wy = gy - y0;
  const int xi0 = min(max((int)x0, 0), WW - 1);
  const int xi1 = min(xi0 + 1, WW - 1);
  const int yi0 = min(max((int)y0, 0), HH - 1);
  const int yi1 = min(yi0 + 1, HH - 1);
  const int s0 = yi0 >> 3, s1 = yi1 >> 3;
  const int j0 = (yi0 & 7) * 8, j1 = (yi1 & 7) * 8;
  const unsigned long long c00 = V8[(size_t)s0 * WW + xi0];
  const unsigned long long c01 = V8[(size_t)s0 * WW + xi1];
  unsigned long long c10 = c00, c11 = c01;
  if (s1 != s0) {                         // ~1/8 of lanes
    c10 = V8[(size_t)s1 * WW + xi0];
    c11 = V8[(size_t)s1 * WW + xi1];
  }
  const float v00 = (float)(signed char)(c00 >> j0);
  const float v01 = (float)(signed char)(c01 >> j0);
  const float v10 = (float)(signed char)(c10 >> j1);
  const float v11 = (float)(signed char)(c11 >> j1);
  return v00 * (1.0f - wx) * (1.0f - wy) + v01 * wx * (1.0f - wy) +
         v10 * (1.0f - wx) * wy + v11 * wx * wy;
}

__global__ __launch_bounds__(256) void gather_k2(const unsigned long long* __restrict__ V8,
                                                 const unsigned int* __restrict__ scaleU,
                                                 const unsigned long long* __restrict__ coorU,
                                                 const float* __restrict__ hX,
                                                 float* __restrict__ out) {
  const int i = blockIdx.x * 256 + threadIdx.x;   // pair index, over n/2
  // 16B of coor = 2 pixels' (x,y); two scalar-typed nontemporal 8B loads
  const unsigned long long c0 = __builtin_nontemporal_load(&coorU[2 * (size_t)i]);
  const unsigned long long c1 = __builtin_nontemporal_load(&coorU[2 * (size_t)i + 1]);
  union { unsigned long long u; float f[2]; } p0, p1;
  p0.u = c0; p1.u = c1;
  const float b0 = gather_one(V8, p0.f[0], p0.f[1]);
  const float b1 = gather_one(V8, p1.f[0], p1.f[1]);
  const float sc = __uint_as_float(*scaleU) * (1.0f / 127.0f);  // wave-uniform
  const unsigned long long hx2 = __builtin_nontemporal_load(
      (const unsigned long long*)(hX + 2 * (size_t)i));
  union { unsigned long long u; float f[2]; } hh; hh.u = hx2;
  union { float f[2]; unsigned long long u; } ov;
  ov.f[0] = b0 * sc + hh.f[0];
  ov.f[1] = b1 * sc + hh.f[1];
  __builtin_nontemporal_store(ov.u, (unsigned long long*)(out + 2 * (size_t)i));
}

extern "C" void kernel_launch(void* const* d_in, const int* in_sizes, int n_in,
                              void* d_out, int out_size, void* d_ws, size_t ws_size,
                              hipStream_t stream) {
  const float* X    = (const float*)d_in[0];
  const float* y    = (const float*)d_in[1];
  const float* hX   = (const float*)d_in[2];
  const float* coor = (const float*)d_in[3];
  float* out = (float*)d_out;

  __half* tcur = (__half*)d_ws;                      // padded t, fp16,  8.65 MB
  __half* bp   = tcur + PadElems;                    // padded b, fp16,  8.65 MB
  __half* t0h  = bp + PadElems;                      // t0 = y-X, fp16,  8.39 MB
  unsigned long long* V8 = (unsigned long long*)(t0h + (size_t)HH * WW);  // 4.19 MB
  unsigned int* scaleU = (unsigned int*)(V8 + (size_t)(HH / 8) * WW);     // 4 B

  const int n = HH * WW;
  const int sblocks = (WW / 512) * (HH / RSP);  // 4 * 256 = 1024 (1-D, swizzled)
  const int vblocks = (WW / 512) * (HH / RV);   // 4 * 128 = 512  (1-D, swizzled)

  zeropad<<<dim3(PROWS, 2, 1), 64, 0, stream>>>(tcur, bp, scaleU);
  sub2pad<<<(n / 4) / 256, 256, 0, stream>>>(y, X, tcur, t0h);

  // iteration 0: -10deg
  passA<0><<<sblocks, 256, 0, stream>>>(tcur, bp);
  passB<0><<<sblocks, 256, 0, stream>>>(bp, tcur);
  // iteration 1: 0deg (vertical, packed)
  passA1v<<<vblocks, 256, 0, stream>>>(tcur, bp);
  passB1v<<<vblocks, 256, 0, stream>>>(bp, tcur);
  // iteration 2: +10deg  (tcur <- D = t0 - t3; global max into scaleU)
  passA<2><<<sblocks, 256, 0, stream>>>(tcur, bp);
  passBF<2><<<sblocks, 256, 0, stream>>>(bp, tcur, t0h, scaleU);

  quantV8<<<((HH / 8) * (WW / 2)) / 256, 256, 0, stream>>>(tcur, scaleU, V8);
  gather_k2<<<(n / 2) / 256, 256, 0, stream>>>(V8, scaleU, (const unsigned long long*)coor, hX, out);
}

// Round 16
// 146.604 us; speedup vs baseline: 1.0183x; 1.0183x over previous
//
#include <hip/hip_runtime.h>
#include <hip/hip_fp16.h>

static constexpr int HH = 2048;
static constexpr int WW = 2048;
static constexpr int PADT = 24;   // top/bottom pad rows
static constexpr int PADL = 8;    // left/right pad cols
static constexpr int SW   = WW + 2 * PADL;          // 2064
static constexpr int PROWS = HH + 2 * PADT;         // 2096
static constexpr size_t PadElems = (size_t)PROWS * SW;
static constexpr int RSP = 16;    // rows/thread, slant passes (packed, 2 cols/thread)
static constexpr int RV = 16;     // rows/thread, vertical passes
static constexpr int NG = 293;    // stride-7 row groups: cell s = rows 7s..7s+7

// segment tables for +10 deg: lval(d)=round(d*tan(10deg))
__device__ constexpr int CS[9] = {-24,-19,-14,-8,-2, 3, 9,15,20};
__device__ constexpr int CE[9] = {-20,-15, -9,-3, 2, 8,14,19,24};
__device__ constexpr int CO[9] = { -4, -3, -2,-1, 0, 1, 2, 3, 4};

union U32H2 { unsigned u; __half2 h; };
__device__ __forceinline__ __half2 u2h(unsigned u) { U32H2 x; x.u = u; return x.h; }
__device__ __forceinline__ unsigned h2u(__half2 h) { U32H2 x; x.h = h; return x.u; }

// XCD band swizzle for 512-block filter grids (4bx x 128by): 16-by (256-row) band/XCD.
__device__ __forceinline__ void swz_f(int& bx, int& by) {
  const int bid = blockIdx.x;             // 0..511
  const int xcd = bid & 7, i = bid >> 3;  // i: 0..63
  by = xcd * 16 + (i & 15);
  bx = i >> 4;                            // 0..3
}

// ---- one slanted segment, packed half2, 2 cols (w2, w2+1), run [SS,EE] at offset OO ----
template<int SS, int EE, int OO, int NROWS>
__device__ __forceinline__ void seg2p(const __half* __restrict__ tp, int h0, int w2,
                                      __half2* __restrict__ acc) {
  constexpr int NR = EE - SS;             // L-1: 4 or 5
  constexpr bool EVEN = ((OO & 1) == 0);
  const size_t st = SW / 2;
  const unsigned* p = (const unsigned*)(tp + (size_t)(h0 + SS + PADT) * SW +
                                        (w2 + PADL + (EVEN ? OO : OO - 1)));
  unsigned ring[NR];
  __half2 s = u2h(0u);
#pragma unroll
  for (int k = 0; k < NR; ++k) {
    unsigned u;
    if constexpr (EVEN) { u = p[k * st]; }
    else { const unsigned ul = p[k * st], ur = p[k * st + 1]; u = (ul >> 16) | (ur << 16); }
    ring[k] = u;
    s = __hadd2(s, u2h(u));
  }
#pragma unroll
  for (int r = 0; r < NROWS; ++r) {
    unsigned u;
    if constexpr (EVEN) { u = p[(NR + r) * st]; }
    else { const unsigned ul = p[(NR + r) * st], ur = p[(NR + r) * st + 1]; u = (ul >> 16) | (ur << 16); }
    const __half2 v = u2h(u);
    acc[r] = __hadd2(acc[r], __hadd2(s, v));
    s = __hadd2(s, __hsub2(v, u2h(ring[r % NR])));
    ring[r % NR] = u;
  }
}

template<int SGN, int NROWS>   // +1 => +10deg, -1 => -10deg
__device__ __forceinline__ void filt_slant2p(const __half* __restrict__ tp, int h0, int w2,
                                             __half2* __restrict__ acc) {
#pragma unroll
  for (int r = 0; r < NROWS; ++r) acc[r] = u2h(0u);
  seg2p<-24, -20, -4 * SGN, NROWS>(tp, h0, w2, acc);
  seg2p<-19, -15, -3 * SGN, NROWS>(tp, h0, w2, acc);
  seg2p<-14,  -9, -2 * SGN, NROWS>(tp, h0, w2, acc);
  seg2p< -8,  -3, -1 * SGN, NROWS>(tp, h0, w2, acc);
  seg2p< -2,   2,  0      , NROWS>(tp, h0, w2, acc);
  seg2p<  3,   8,  1 * SGN, NROWS>(tp, h0, w2, acc);
  seg2p<  9,  14,  2 * SGN, NROWS>(tp, h0, w2, acc);
  seg2p< 15,  19,  3 * SGN, NROWS>(tp, h0, w2, acc);
  seg2p< 20,  24,  4 * SGN, NROWS>(tp, h0, w2, acc);
}

// analytic 1/N for the slant filters (A=0 => -10deg, A=2 => +10deg)
template<int A>
__device__ __forceinline__ float rcpcnt(int h, int w) {
  if (h >= 24 && h <= 2023 && w >= 4 && w <= 2043) return 1.0f / 49.0f;
  int cnt = 0;
  const int sgn = (A == 0) ? -1 : 1;
#pragma unroll
  for (int j = 0; j < 9; ++j) {
    const int ww = w + sgn * CO[j];
    const int ov = min(h + CE[j], HH - 1) - max(h + CS[j], 0) + 1;
    if (ww >= 0 && ww < WW && ov > 0) cnt += ov;
  }
  return 1.0f / (float)cnt;
}

// 1/N for the vertical filter
__device__ __forceinline__ float rcpcnt1(int h) {
  return 1.0f / (float)(min(h + 24, HH - 1) - max(h - 24, 0) + 1);
}

// ---- slant pass A: bp = filt(tcur)/N  (packed, 2 cols/thread) ----
template<int A>
__global__ __launch_bounds__(256) void passA(const __half* __restrict__ tcur,
                                             __half* __restrict__ bp) {
  int bx, by; swz_f(bx, by);
  const int w2 = (bx * 256 + threadIdx.x) * 2;
  const int h0 = by * RSP;
  __half2 acc[RSP];
  filt_slant2p<(A == 0) ? -1 : 1, RSP>(tcur, h0, w2, acc);
#pragma unroll
  for (int r = 0; r < RSP; ++r) {
    const int h = h0 + r;
    const float2 f = __half22float2(acc[r]);
    *(unsigned*)(bp + (size_t)(h + PADT) * SW + (w2 + PADL)) =
        h2u(__floats2half2_rn(f.x * rcpcnt<A>(h, w2), f.y * rcpcnt<A>(h, w2 + 1)));
  }
}

// ---- slant pass B (mid): tcur -= filt(bp)/N (in place, packed) ----
template<int A>
__global__ __launch_bounds__(256) void passB(const __half* __restrict__ bp,
                                             __half* __restrict__ tcur) {
  int bx, by; swz_f(bx, by);
  const int w2 = (bx * 256 + threadIdx.x) * 2;
  const int h0 = by * RSP;
  __half2 acc[RSP];
  filt_slant2p<(A == 0) ? -1 : 1, RSP>(bp, h0, w2, acc);
#pragma unroll
  for (int r = 0; r < RSP; ++r) {
    const int h = h0 + r;
    unsigned* o = (unsigned*)(tcur + (size_t)(h + PADT) * SW + (w2 + PADL));
    const float2 cur = __half22float2(u2h(*o));
    const float2 f = __half22float2(acc[r]);
    *o = h2u(__floats2half2_rn(cur.x - f.x * rcpcnt<A>(h, w2),
                               cur.y - f.y * rcpcnt<A>(h, w2 + 1)));
  }
}

// ---- final slant pass B: res = t0 - (tcur - filt(bp)/N); tcur <- res; global max ----
template<int A>
__global__ __launch_bounds__(256) void passBF(const __half* __restrict__ bp,
                                              __half* __restrict__ tcur,
                                              const __half* __restrict__ t0h,
                                              unsigned int* __restrict__ scaleU) {
  int bx, by; swz_f(bx, by);
  const int w2 = (bx * 256 + threadIdx.x) * 2;
  const int h0 = by * RSP;
  __half2 acc[RSP];
  filt_slant2p<(A == 0) ? -1 : 1, RSP>(bp, h0, w2, acc);
  float m = 0.0f;
#pragma unroll
  for (int r = 0; r < RSP; ++r) {
    const int h = h0 + r;
    const float2 t0 = __half22float2(u2h(*(const unsigned*)(t0h + (size_t)h * WW + w2)));
    unsigned* o = (unsigned*)(tcur + (size_t)(h + PADT) * SW + (w2 + PADL));
    const float2 cur = __half22float2(u2h(*o));
    const float2 f = __half22float2(acc[r]);
    const float rx = t0.x - cur.x + f.x * rcpcnt<A>(h, w2);
    const float ry = t0.y - cur.y + f.y * rcpcnt<A>(h, w2 + 1);
    *o = h2u(__floats2half2_rn(rx, ry));
    m = fmaxf(m, fmaxf(fabsf(rx), fabsf(ry)));
  }
#pragma unroll
  for (int off = 32; off >= 1; off >>= 1) m = fmaxf(m, __shfl_xor(m, off));
  __shared__ float red[4];
  if ((threadIdx.x & 63) == 0) red[threadIdx.x >> 6] = m;
  __syncthreads();
  if (threadIdx.x == 0) {
    const float bm = fmaxf(fmaxf(red[0], red[1]), fmaxf(red[2], red[3]));
    atomicMax(scaleU, __float_as_uint(bm));
  }
}

// ---- vertical (0 deg) passes, packed half2, 2 cols/thread ----
__global__ __launch_bounds__(256) void passA1v(const __half* __restrict__ tcur,
                                               __half* __restrict__ bp) {
  int bx, by; swz_f(bx, by);
  const int w2 = (bx * 256 + threadIdx.x) * 2;
  const int h0 = by * RV;
  const size_t st = SW / 2;
  const unsigned* p = (const unsigned*)(tcur + (size_t)(h0 - 24 + PADT) * SW + (w2 + PADL));
  __half2 s = u2h(0u);
#pragma unroll
  for (int k = 0; k < 48; ++k) s = __hadd2(s, u2h(p[k * st]));
#pragma unroll
  for (int r = 0; r < RV; ++r) {
    const int h = h0 + r;
    const __half2 vin = u2h(p[(48 + r) * st]);
    const float2 f = __half22float2(__hadd2(s, vin));
    const float rc = rcpcnt1(h);
    *(unsigned*)(bp + (size_t)(h + PADT) * SW + (w2 + PADL)) =
        h2u(__floats2half2_rn(f.x * rc, f.y * rc));
    s = __hadd2(s, __hsub2(vin, u2h(p[r * st])));
  }
}

__global__ __launch_bounds__(256) void passB1v(const __half* __restrict__ bp,
                                               __half* __restrict__ tcur) {
  int bx, by; swz_f(bx, by);
  const int w2 = (bx * 256 + threadIdx.x) * 2;
  const int h0 = by * RV;
  const size_t st = SW / 2;
  const unsigned* p = (const unsigned*)(bp + (size_t)(h0 - 24 + PADT) * SW + (w2 + PADL));
  __half2 s = u2h(0u);
#pragma unroll
  for (int k = 0; k < 48; ++k) s = __hadd2(s, u2h(p[k * st]));
#pragma unroll
  for (int r = 0; r < RV; ++r) {
    const int h = h0 + r;
    const __half2 vin = u2h(p[(48 + r) * st]);
    const float2 f = __half22float2(__hadd2(s, vin));
    const float rc = rcpcnt1(h);
    unsigned* o = (unsigned*)(tcur + (size_t)(h + PADT) * SW + (w2 + PADL));
    const float2 cur = __half22float2(u2h(*o));
    *o = h2u(__floats2half2_rn(cur.x - f.x * rc, cur.y - f.y * rc));
    s = __hadd2(s, __hsub2(vin, u2h(p[r * st])));
  }
}

// ---- quantize D (in tcur) into stride-7 8-row-packed int8 cells:
// V8[s*WW + x] byte j = q[7s+j][x], s in [0,NG); 2 cells/thread ----
__global__ __launch_bounds__(256) void quantV8s7(const __half* __restrict__ tcur,
                                                 const unsigned int* __restrict__ scaleU,
                                                 unsigned long long* __restrict__ V8) {
  const int i = blockIdx.x * 256 + threadIdx.x;   // over NG * (WW/2)
  const int s = i >> 10, x2 = (i & 1023) * 2;
  const float mg = __uint_as_float(*scaleU);
  const float inv = (mg > 0.0f) ? 127.0f / mg : 0.0f;
  const unsigned* base = (const unsigned*)(tcur + (size_t)(7 * s + PADT) * SW + (x2 + PADL));
  const size_t st = SW / 2;
  unsigned long long va = 0, vb = 0;
#pragma unroll
  for (int j = 0; j < 8; ++j) {   // rows 7s..7s+7 (rows >= HH read pad zeros: benign)
    const float2 f = __half22float2(u2h(base[(size_t)j * st]));
    const int qa = min(max((int)rintf(f.x * inv), -127), 127);
    const int qb = min(max((int)rintf(f.y * inv), -127), 127);
    va |= (unsigned long long)(unsigned char)(qa & 0xff) << (8 * j);
    vb |= (unsigned long long)(unsigned char)(qb & 0xff) << (8 * j);
  }
  unsigned long long* o = V8 + (size_t)s * WW + x2;
  o[0] = va; o[1] = vb;
}

// ---- init: interior tcur/t0h = y - X (float4), pad frames zeroed, scaleU zeroed ----
__global__ __launch_bounds__(256) void initk(const float* __restrict__ y,
                                             const float* __restrict__ X,
                                             __half* __restrict__ tcur,
                                             __half* __restrict__ t0h,
                                             __half* __restrict__ bp,
                                             unsigned int* __restrict__ scaleU) {
  const int b = blockIdx.x;
  if (b < 4096) {
    const int i = b * 256 + threadIdx.x;          // over n/4
    const int p = i * 4;
    const int h = p >> 11, w = p & (WW - 1);
    const float4 Y = ((const float4*)y)[i];
    const float4 Xv = ((const float4*)X)[i];
    union { __half2 h2; unsigned u; } a, c;
    a.h2 = __floats2half2_rn(Y.x - Xv.x, Y.y - Xv.y);
    c.h2 = __floats2half2_rn(Y.z - Xv.z, Y.w - Xv.w);
    uint2 o; o.x = a.u; o.y = c.u;
    *(uint2*)(tcur + (size_t)(h + PADT) * SW + (w + PADL)) = o;
    *(uint2*)(t0h + (size_t)p) = o;
  } else {
    const int row = b - 4096;                     // 0..PROWS-1
    if (row == 0 && threadIdx.x == 0) *scaleU = 0u;
    __half* rt = tcur + (size_t)row * SW;
    __half* rb = bp + (size_t)row * SW;
    const __half z = __float2half(0.0f);
    if (row < PADT || row >= PADT + HH) {
      for (int c = threadIdx.x; c < SW; c += 256) { rt[c] = z; rb[c] = z; }
    } else if (threadIdx.x < 2 * PADL) {
      const int c = (threadIdx.x < PADL) ? threadIdx.x : (PADL + WW + threadIdx.x - PADL);
      rt[c] = z; rb[c] = z;
    }
  }
}

// ---- gather, 1 px/thread, stride-7 cells: EXACTLY 2 divergent loads/px ----
__global__ __launch_bounds__(256) void gather_k(const unsigned long long* __restrict__ V8,
                                                const unsigned int* __restrict__ scaleU,
                                                const unsigned long long* __restrict__ coorU,
                                                const float* __restrict__ hX,
                                                float* __restrict__ out) {
  const int i = blockIdx.x * 256 + threadIdx.x;
  const unsigned long long cu = __builtin_nontemporal_load(&coorU[i]);
  union { unsigned long long u; float f[2]; } cc; cc.u = cu;
  // coor in [-1,1] -> reflect degenerates to clamp
  const float gx = fminf(fmaxf((cc.f[0] + 1.0f) * 0.5f * (float)(WW - 1), 0.0f), (float)(WW - 1));
  const float gy = fminf(fmaxf((cc.f[1] + 1.0f) * 0.5f * (float)(HH - 1), 0.0f), (float)(HH - 1));
  const float x0 = floorf(gx), y0 = floorf(gy);
  const float wx = gx - x0, wy = gy - y0;
  const int xi0 = min(max((int)x0, 0), WW - 1);
  const int xi1 = min(xi0 + 1, WW - 1);
  const int yi0 = min(max((int)y0, 0), HH - 1);
  const int s0 = (yi0 * 9363) >> 16;            // exact yi0/7 for yi0 < 91750
  const int j0 = (yi0 - s0 * 7) * 8;            // byte shift; j0/8 <= 6 always
  const unsigned long long c0 = V8[(size_t)s0 * WW + xi0];  // rows yi0, yi0+1 both inside
  const unsigned long long c1 = V8[(size_t)s0 * WW + xi1];
  const float v00 = (float)(signed char)(c0 >> j0);
  const float v10 = (float)(signed char)(c0 >> (j0 + 8));
  const float v01 = (float)(signed char)(c1 >> j0);
  const float v11 = (float)(signed char)(c1 >> (j0 + 8));
  const float sc = __uint_as_float(*scaleU) * (1.0f / 127.0f);  // wave-uniform
  const float hx = __builtin_nontemporal_load(&hX[i]);
  const float bil = v00 * (1.0f - wx) * (1.0f - wy) + v01 * wx * (1.0f - wy) +
                    v10 * (1.0f - wx) * wy + v11 * wx * wy;
  __builtin_nontemporal_store(bil * sc + hx, &out[i]);
}

extern "C" void kernel_launch(void* const* d_in, const int* in_sizes, int n_in,
                              void* d_out, int out_size, void* d_ws, size_t ws_size,
                              hipStream_t stream) {
  const float* X    = (const float*)d_in[0];
  const float* y    = (const float*)d_in[1];
  const float* hX   = (const float*)d_in[2];
  const float* coor = (const float*)d_in[3];
  float* out = (float*)d_out;

  __half* tcur = (__half*)d_ws;                      // padded t, fp16,  8.65 MB
  __half* bp   = tcur + PadElems;                    // padded b, fp16,  8.65 MB
  __half* t0h  = bp + PadElems;                      // t0 = y-X, fp16,  8.39 MB
  unsigned long long* V8 = (unsigned long long*)(t0h + (size_t)HH * WW);  // 4.80 MB
  unsigned int* scaleU = (unsigned int*)(V8 + (size_t)NG * WW);           // 4 B

  const int n = HH * WW;
  const int fblocks = (WW / 512) * (HH / RSP);  // 4 * 128 = 512 (1-D, swizzled)
  const int qblocks = (NG * (WW / 2)) / 256;    // 1172

  initk<<<4096 + PROWS, 256, 0, stream>>>(y, X, tcur, t0h, bp, scaleU);

  // iteration 0: -10deg
  passA<0><<<fblocks, 256, 0, stream>>>(tcur, bp);
  passB<0><<<fblocks, 256, 0, stream>>>(bp, tcur);
  // iteration 1: 0deg (vertical, packed)
  passA1v<<<fblocks, 256, 0, stream>>>(tcur, bp);
  passB1v<<<fblocks, 256, 0, stream>>>(bp, tcur);
  // iteration 2: +10deg  (tcur <- D = t0 - t3; global max into scaleU)
  passA<2><<<fblocks, 256, 0, stream>>>(tcur, bp);
  passBF<2><<<fblocks, 256, 0, stream>>>(bp, tcur, t0h, scaleU);

  quantV8s7<<<qblocks, 256, 0, stream>>>(tcur, scaleU, V8);
  gather_k<<<n / 256, 256, 0, stream>>>(V8, scaleU, (const unsigned long long*)coor, hX, out);
}

// Round 17
// 139.627 us; speedup vs baseline: 1.0692x; 1.0500x over previous
//
#include <hip/hip_runtime.h>
#include <hip/hip_fp16.h>

static constexpr int HH = 2048;
static constexpr int WW = 2048;
static constexpr int PADT = 24;   // top/bottom pad rows
static constexpr int PADL = 8;    // left/right pad cols
static constexpr int SW   = WW + 2 * PADL;          // 2064
static constexpr int PROWS = HH + 2 * PADT;         // 2096
static constexpr size_t PadElems = (size_t)PROWS * SW;
static constexpr int RSP = 16;    // rows/thread, slant passes (packed, 2 cols/thread)
static constexpr int RV = 16;     // rows/thread, vertical passes

// segment tables for +10 deg: lval(d)=round(d*tan(10deg))
__device__ constexpr int CS[9] = {-24,-19,-14,-8,-2, 3, 9,15,20};
__device__ constexpr int CE[9] = {-20,-15, -9,-3, 2, 8,14,19,24};
__device__ constexpr int CO[9] = { -4, -3, -2,-1, 0, 1, 2, 3, 4};

union U32H2 { unsigned u; __half2 h; };
__device__ __forceinline__ __half2 u2h(unsigned u) { U32H2 x; x.u = u; return x.h; }
__device__ __forceinline__ unsigned h2u(__half2 h) { U32H2 x; x.h = h; return x.u; }

// XCD band swizzle for 512-block filter grids (4bx x 128by): 16-by (256-row) band/XCD.
__device__ __forceinline__ void swz_f(int& bx, int& by) {
  const int bid = blockIdx.x;             // 0..511
  const int xcd = bid & 7, i = bid >> 3;  // i: 0..63
  by = xcd * 16 + (i & 15);
  bx = i >> 4;                            // 0..3
}

// ---- one slanted segment, packed half2, 2 cols (w2, w2+1), run [SS,EE] at offset OO ----
template<int SS, int EE, int OO, int NROWS>
__device__ __forceinline__ void seg2p(const __half* __restrict__ tp, int h0, int w2,
                                      __half2* __restrict__ acc) {
  constexpr int NR = EE - SS;             // L-1: 4 or 5
  constexpr bool EVEN = ((OO & 1) == 0);
  const size_t st = SW / 2;
  const unsigned* p = (const unsigned*)(tp + (size_t)(h0 + SS + PADT) * SW +
                                        (w2 + PADL + (EVEN ? OO : OO - 1)));
  unsigned ring[NR];
  __half2 s = u2h(0u);
#pragma unroll
  for (int k = 0; k < NR; ++k) {
    unsigned u;
    if constexpr (EVEN) { u = p[k * st]; }
    else { const unsigned ul = p[k * st], ur = p[k * st + 1]; u = (ul >> 16) | (ur << 16); }
    ring[k] = u;
    s = __hadd2(s, u2h(u));
  }
#pragma unroll
  for (int r = 0; r < NROWS; ++r) {
    unsigned u;
    if constexpr (EVEN) { u = p[(NR + r) * st]; }
    else { const unsigned ul = p[(NR + r) * st], ur = p[(NR + r) * st + 1]; u = (ul >> 16) | (ur << 16); }
    const __half2 v = u2h(u);
    acc[r] = __hadd2(acc[r], __hadd2(s, v));
    s = __hadd2(s, __hsub2(v, u2h(ring[r % NR])));
    ring[r % NR] = u;
  }
}

template<int SGN, int NROWS>   // +1 => +10deg, -1 => -10deg
__device__ __forceinline__ void filt_slant2p(const __half* __restrict__ tp, int h0, int w2,
                                             __half2* __restrict__ acc) {
#pragma unroll
  for (int r = 0; r < NROWS; ++r) acc[r] = u2h(0u);
  seg2p<-24, -20, -4 * SGN, NROWS>(tp, h0, w2, acc);
  seg2p<-19, -15, -3 * SGN, NROWS>(tp, h0, w2, acc);
  seg2p<-14,  -9, -2 * SGN, NROWS>(tp, h0, w2, acc);
  seg2p< -8,  -3, -1 * SGN, NROWS>(tp, h0, w2, acc);
  seg2p< -2,   2,  0      , NROWS>(tp, h0, w2, acc);
  seg2p<  3,   8,  1 * SGN, NROWS>(tp, h0, w2, acc);
  seg2p<  9,  14,  2 * SGN, NROWS>(tp, h0, w2, acc);
  seg2p< 15,  19,  3 * SGN, NROWS>(tp, h0, w2, acc);
  seg2p< 20,  24,  4 * SGN, NROWS>(tp, h0, w2, acc);
}

// analytic 1/N for the slant filters (A=0 => -10deg, A=2 => +10deg)
template<int A>
__device__ __forceinline__ float rcpcnt(int h, int w) {
  if (h >= 24 && h <= 2023 && w >= 4 && w <= 2043) return 1.0f / 49.0f;
  int cnt = 0;
  const int sgn = (A == 0) ? -1 : 1;
#pragma unroll
  for (int j = 0; j < 9; ++j) {
    const int ww = w + sgn * CO[j];
    const int ov = min(h + CE[j], HH - 1) - max(h + CS[j], 0) + 1;
    if (ww >= 0 && ww < WW && ov > 0) cnt += ov;
  }
  return 1.0f / (float)cnt;
}

// 1/N for the vertical filter
__device__ __forceinline__ float rcpcnt1(int h) {
  return 1.0f / (float)(min(h + 24, HH - 1) - max(h - 24, 0) + 1);
}

// ---- slant pass A: bp = filt(tcur)/N  (packed, 2 cols/thread) ----
template<int A>
__global__ __launch_bounds__(256) void passA(const __half* __restrict__ tcur,
                                             __half* __restrict__ bp) {
  int bx, by; swz_f(bx, by);
  const int w2 = (bx * 256 + threadIdx.x) * 2;
  const int h0 = by * RSP;
  __half2 acc[RSP];
  filt_slant2p<(A == 0) ? -1 : 1, RSP>(tcur, h0, w2, acc);
#pragma unroll
  for (int r = 0; r < RSP; ++r) {
    const int h = h0 + r;
    const float2 f = __half22float2(acc[r]);
    *(unsigned*)(bp + (size_t)(h + PADT) * SW + (w2 + PADL)) =
        h2u(__floats2half2_rn(f.x * rcpcnt<A>(h, w2), f.y * rcpcnt<A>(h, w2 + 1)));
  }
}

// ---- slant pass B (mid): tcur -= filt(bp)/N (in place, packed) ----
template<int A>
__global__ __launch_bounds__(256) void passB(const __half* __restrict__ bp,
                                             __half* __restrict__ tcur) {
  int bx, by; swz_f(bx, by);
  const int w2 = (bx * 256 + threadIdx.x) * 2;
  const int h0 = by * RSP;
  __half2 acc[RSP];
  filt_slant2p<(A == 0) ? -1 : 1, RSP>(bp, h0, w2, acc);
#pragma unroll
  for (int r = 0; r < RSP; ++r) {
    const int h = h0 + r;
    unsigned* o = (unsigned*)(tcur + (size_t)(h + PADT) * SW + (w2 + PADL));
    const float2 cur = __half22float2(u2h(*o));
    const float2 f = __half22float2(acc[r]);
    *o = h2u(__floats2half2_rn(cur.x - f.x * rcpcnt<A>(h, w2),
                               cur.y - f.y * rcpcnt<A>(h, w2 + 1)));
  }
}

// ---- final slant pass B: res = t0 - (tcur - filt(bp)/N); tcur <- res; global max ----
template<int A>
__global__ __launch_bounds__(256) void passBF(const __half* __restrict__ bp,
                                              __half* __restrict__ tcur,
                                              const __half* __restrict__ t0h,
                                              unsigned int* __restrict__ scaleU) {
  int bx, by; swz_f(bx, by);
  const int w2 = (bx * 256 + threadIdx.x) * 2;
  const int h0 = by * RSP;
  __half2 acc[RSP];
  filt_slant2p<(A == 0) ? -1 : 1, RSP>(bp, h0, w2, acc);
  float m = 0.0f;
#pragma unroll
  for (int r = 0; r < RSP; ++r) {
    const int h = h0 + r;
    const float2 t0 = __half22float2(u2h(*(const unsigned*)(t0h + (size_t)h * WW + w2)));
    unsigned* o = (unsigned*)(tcur + (size_t)(h + PADT) * SW + (w2 + PADL));
    const float2 cur = __half22float2(u2h(*o));
    const float2 f = __half22float2(acc[r]);
    const float rx = t0.x - cur.x + f.x * rcpcnt<A>(h, w2);
    const float ry = t0.y - cur.y + f.y * rcpcnt<A>(h, w2 + 1);
    *o = h2u(__floats2half2_rn(rx, ry));
    m = fmaxf(m, fmaxf(fabsf(rx), fabsf(ry)));
  }
#pragma unroll
  for (int off = 32; off >= 1; off >>= 1) m = fmaxf(m, __shfl_xor(m, off));
  __shared__ float red[4];
  if ((threadIdx.x & 63) == 0) red[threadIdx.x >> 6] = m;
  __syncthreads();
  if (threadIdx.x == 0) {
    const float bm = fmaxf(fmaxf(red[0], red[1]), fmaxf(red[2], red[3]));
    atomicMax(scaleU, __float_as_uint(bm));
  }
}

// ---- vertical (0 deg) passes, packed half2, 2 cols/thread ----
__global__ __launch_bounds__(256) void passA1v(const __half* __restrict__ tcur,
                                               __half* __restrict__ bp) {
  int bx, by; swz_f(bx, by);
  const int w2 = (bx * 256 + threadIdx.x) * 2;
  const int h0 = by * RV;
  const size_t st = SW / 2;
  const unsigned* p = (const unsigned*)(tcur + (size_t)(h0 - 24 + PADT) * SW + (w2 + PADL));
  __half2 s = u2h(0u);
#pragma unroll
  for (int k = 0; k < 48; ++k) s = __hadd2(s, u2h(p[k * st]));
#pragma unroll
  for (int r = 0; r < RV; ++r) {
    const int h = h0 + r;
    const __half2 vin = u2h(p[(48 + r) * st]);
    const float2 f = __half22float2(__hadd2(s, vin));
    const float rc = rcpcnt1(h);
    *(unsigned*)(bp + (size_t)(h + PADT) * SW + (w2 + PADL)) =
        h2u(__floats2half2_rn(f.x * rc, f.y * rc));
    s = __hadd2(s, __hsub2(vin, u2h(p[r * st])));
  }
}

__global__ __launch_bounds__(256) void passB1v(const __half* __restrict__ bp,
                                               __half* __restrict__ tcur) {
  int bx, by; swz_f(bx, by);
  const int w2 = (bx * 256 + threadIdx.x) * 2;
  const int h0 = by * RV;
  const size_t st = SW / 2;
  const unsigned* p = (const unsigned*)(bp + (size_t)(h0 - 24 + PADT) * SW + (w2 + PADL));
  __half2 s = u2h(0u);
#pragma unroll
  for (int k = 0; k < 48; ++k) s = __hadd2(s, u2h(p[k * st]));
#pragma unroll
  for (int r = 0; r < RV; ++r) {
    const int h = h0 + r;
    const __half2 vin = u2h(p[(48 + r) * st]);
    const float2 f = __half22float2(__hadd2(s, vin));
    const float rc = rcpcnt1(h);
    unsigned* o = (unsigned*)(tcur + (size_t)(h + PADT) * SW + (w2 + PADL));
    const float2 cur = __half22float2(u2h(*o));
    *o = h2u(__floats2half2_rn(cur.x - f.x * rc, cur.y - f.y * rc));
    s = __hadd2(s, __hsub2(vin, u2h(p[r * st])));
  }
}

// ---- quantize D into 8-row-packed int8 cells (stride-8, aligned), 2 cells/thread ----
__global__ __launch_bounds__(256) void quantV8(const __half* __restrict__ tcur,
                                               const unsigned int* __restrict__ scaleU,
                                               unsigned long long* __restrict__ V8) {
  const int i = blockIdx.x * 256 + threadIdx.x;   // over (HH/8) * (WW/2)
  const int s = i >> 10, x2 = (i & 1023) * 2;
  const float mg = __uint_as_float(*scaleU);
  const float inv = (mg > 0.0f) ? 127.0f / mg : 0.0f;
  const unsigned* base = (const unsigned*)(tcur + (size_t)(8 * s + PADT) * SW + (x2 + PADL));
  const size_t st = SW / 2;
  unsigned long long va = 0, vb = 0;
#pragma unroll
  for (int j = 0; j < 8; ++j) {
    const float2 f = __half22float2(u2h(base[(size_t)j * st]));
    const int qa = min(max((int)rintf(f.x * inv), -127), 127);
    const int qb = min(max((int)rintf(f.y * inv), -127), 127);
    va |= (unsigned long long)(unsigned char)(qa & 0xff) << (8 * j);
    vb |= (unsigned long long)(unsigned char)(qb & 0xff) << (8 * j);
  }
  unsigned long long* o = V8 + (size_t)s * WW + x2;
  o[0] = va; o[1] = vb;
}

// ---- init: interior tcur/t0h = y - X (float4), pad frames zeroed, scaleU zeroed ----
__global__ __launch_bounds__(256) void initk(const float* __restrict__ y,
                                             const float* __restrict__ X,
                                             __half* __restrict__ tcur,
                                             __half* __restrict__ t0h,
                                             __half* __restrict__ bp,
                                             unsigned int* __restrict__ scaleU) {
  const int b = blockIdx.x;
  if (b < 4096) {
    const int i = b * 256 + threadIdx.x;          // over n/4
    const int p = i * 4;
    const int h = p >> 11, w = p & (WW - 1);
    const float4 Y = ((const float4*)y)[i];
    const float4 Xv = ((const float4*)X)[i];
    union { __half2 h2; unsigned u; } a, c;
    a.h2 = __floats2half2_rn(Y.x - Xv.x, Y.y - Xv.y);
    c.h2 = __floats2half2_rn(Y.z - Xv.z, Y.w - Xv.w);
    uint2 o; o.x = a.u; o.y = c.u;
    *(uint2*)(tcur + (size_t)(h + PADT) * SW + (w + PADL)) = o;
    *(uint2*)(t0h + (size_t)p) = o;
  } else {
    const int row = b - 4096;                     // 0..PROWS-1
    if (row == 0 && threadIdx.x == 0) *scaleU = 0u;
    __half* rt = tcur + (size_t)row * SW;
    __half* rb = bp + (size_t)row * SW;
    const __half z = __float2half(0.0f);
    if (row < PADT || row >= PADT + HH) {
      for (int c = threadIdx.x; c < SW; c += 256) { rt[c] = z; rb[c] = z; }
    } else if (threadIdx.x < 2 * PADL) {
      const int c = (threadIdx.x < PADL) ? threadIdx.x : (PADL + WW + threadIdx.x - PADL);
      rt[c] = z; rb[c] = z;
    }
  }
}

// ---- gather, 1 px/thread, stride-8 V8 cells (proven local optimum) ----
__global__ __launch_bounds__(256) void gather_k(const unsigned long long* __restrict__ V8,
                                                const unsigned int* __restrict__ scaleU,
                                                const unsigned long long* __restrict__ coorU,
                                                const float* __restrict__ hX,
                                                float* __restrict__ out) {
  const int i = blockIdx.x * 256 + threadIdx.x;
  const unsigned long long cu = __builtin_nontemporal_load(&coorU[i]);
  union { unsigned long long u; float f[2]; } cc; cc.u = cu;
  // coor in [-1,1] -> reflect degenerates to clamp
  const float gx = fminf(fmaxf((cc.f[0] + 1.0f) * 0.5f * (float)(WW - 1), 0.0f), (float)(WW - 1));
  const float gy = fminf(fmaxf((cc.f[1] + 1.0f) * 0.5f * (float)(HH - 1), 0.0f), (float)(HH - 1));
  const float x0 = floorf(gx), y0 = floorf(gy);
  const float wx = gx - x0, wy = gy - y0;
  const int xi0 = min(max((int)x0, 0), WW - 1);
  const int xi1 = min(xi0 + 1, WW - 1);
  const int yi0 = min(max((int)y0, 0), HH - 1);
  const int yi1 = min(yi0 + 1, HH - 1);
  const int s0 = yi0 >> 3, s1 = yi1 >> 3;
  const int j0 = (yi0 & 7) * 8, j1 = (yi1 & 7) * 8;
  const unsigned long long c00 = V8[(size_t)s0 * WW + xi0];
  const unsigned long long c01 = V8[(size_t)s0 * WW + xi1];
  unsigned long long c10 = c00, c11 = c01;
  if (s1 != s0) {                         // ~1/8 of lanes
    c10 = V8[(size_t)s1 * WW + xi0];
    c11 = V8[(size_t)s1 * WW + xi1];
  }
  const float v00 = (float)(signed char)(c00 >> j0);
  const float v01 = (float)(signed char)(c01 >> j0);
  const float v10 = (float)(signed char)(c10 >> j1);
  const float v11 = (float)(signed char)(c11 >> j1);
  const float sc = __uint_as_float(*scaleU) * (1.0f / 127.0f);  // wave-uniform
  const float hx = __builtin_nontemporal_load(&hX[i]);
  const float bil = v00 * (1.0f - wx) * (1.0f - wy) + v01 * wx * (1.0f - wy) +
                    v10 * (1.0f - wx) * wy + v11 * wx * wy;
  __builtin_nontemporal_store(bil * sc + hx, &out[i]);
}

extern "C" void kernel_launch(void* const* d_in, const int* in_sizes, int n_in,
                              void* d_out, int out_size, void* d_ws, size_t ws_size,
                              hipStream_t stream) {
  const float* X    = (const float*)d_in[0];
  const float* y    = (const float*)d_in[1];
  const float* hX   = (const float*)d_in[2];
  const float* coor = (const float*)d_in[3];
  float* out = (float*)d_out;

  __half* tcur = (__half*)d_ws;                      // padded t, fp16,  8.65 MB
  __half* bp   = tcur + PadElems;                    // padded b, fp16,  8.65 MB
  __half* t0h  = bp + PadElems;                      // t0 = y-X, fp16,  8.39 MB
  unsigned long long* V8 = (unsigned long long*)(t0h + (size_t)HH * WW);  // 4.19 MB
  unsigned int* scaleU = (unsigned int*)(V8 + (size_t)(HH / 8) * WW);     // 4 B

  const int n = HH * WW;
  const int fblocks = (WW / 512) * (HH / RSP);  // 4 * 128 = 512 (1-D, swizzled)

  initk<<<4096 + PROWS, 256, 0, stream>>>(y, X, tcur, t0h, bp, scaleU);

  // iteration 0: -10deg
  passA<0><<<fblocks, 256, 0, stream>>>(tcur, bp);
  passB<0><<<fblocks, 256, 0, stream>>>(bp, tcur);
  // iteration 1: 0deg (vertical, packed)
  passA1v<<<fblocks, 256, 0, stream>>>(tcur, bp);
  passB1v<<<fblocks, 256, 0, stream>>>(bp, tcur);
  // iteration 2: +10deg  (tcur <- D = t0 - t3; global max into scaleU)
  passA<2><<<fblocks, 256, 0, stream>>>(tcur, bp);
  passBF<2><<<fblocks, 256, 0, stream>>>(bp, tcur, t0h, scaleU);

  quantV8<<<((HH / 8) * (WW / 2)) / 256, 256, 0, stream>>>(tcur, scaleU, V8);
  gather_k<<<n / 256, 256, 0, stream>>>(V8, scaleU, (const unsigned long long*)coor, hX, out);
}